// Round 6
// baseline (94.776 us; speedup 1.0000x reference)
//
#include <hip/hip_runtime.h>
#include <hip/hip_bf16.h>

#define NATOMS 2048
#define K 48
#define NR 5
#define NM 12
#define ND 17
#define HID 64

#define PI_F 3.14159265358979f
#define CUT 3.0f
#define RMIN_F 3.5f
#define AFC (-6.28318530717959f)   /* pi/(CUT-RMIN) = pi/(-0.5) */
#define POC (PI_F / CUT)           /* pi/3 */
#define SQ 0.816496580927726f      /* sqrt(2/3) */
#define CMC (-0.132231404958678f)  /* -16/121 */
/* exp2-folded constants (x * log2(e)) */
#define N4L (-5.77078016355585f)   /* -4 * log2e */
#define E1L (2.09846551402031f)    /* (16/11) * log2e */
#define TL2 (2.88539008177793f)    /* 2 * log2e */

// Packed bf16 weight layouts (built once per launch by k_prep).
__device__ unsigned short g_w1t[64 * 32];  // [n=h][k=j]  (k>=17 zero)
__device__ unsigned short g_w2t[64 * 64];  // [n=h2][k=h1]
__device__ unsigned short g_w2r[64 * 64];  // [n=h1][k=h2]
__device__ unsigned short g_w1r[32 * 64];  // [n=j][k=h]  (n>=17 zero)

using frag_ab = __attribute__((ext_vector_type(8))) short;
using frag_cd = __attribute__((ext_vector_type(4))) float;
using f2 = __attribute__((ext_vector_type(2))) float;
using f4 = __attribute__((ext_vector_type(4))) float;

__device__ __forceinline__ float fast_tanh(float x) {
    const float t = __builtin_amdgcn_exp2f(TL2 * x);
    return 1.0f - 2.0f * __builtin_amdgcn_rcpf(t + 1.0f);
}

__device__ __forceinline__ unsigned short f2bs(float x) {
    __hip_bfloat16 b = __float2bfloat16(x);
    return __builtin_bit_cast(unsigned short, b);
}

__device__ __forceinline__ float bs2f(unsigned short u) {
    return __builtin_bit_cast(float, ((unsigned)u) << 16);
}

// DPP cross-lane add. 0xB1/0x4E = quad_perm xor1/xor2 (butterfly).
// 0x110|s = row_shr s (16-lane sum lands in lane 15 of each DPP row).
template <int CTRL>
__device__ __forceinline__ float dpp_add(float x) {
    const int y = __builtin_amdgcn_update_dpp(
        0, __builtin_bit_cast(int, x), CTRL, 0xF, 0xF, true);
    return x + __builtin_bit_cast(float, y);
}

// ---------------- Kernel 0: pack weights into MFMA-ready bf16 layouts -----
__global__ __launch_bounds__(256) void k_prep(const float* __restrict__ W1,
                                              const float* __restrict__ W2) {
    const int i = blockIdx.x * 256 + threadIdx.x;  // grid covers 12288
    if (i < 2048) {                                   // W1T[n][k]
        const int n = i >> 5, k = i & 31;
        g_w1t[i] = (k < ND) ? f2bs(W1[k * HID + n]) : (unsigned short)0;
    } else if (i < 2048 + 4096) {                     // W2T[n][k]
        const int j = i - 2048, n = j >> 6, k = j & 63;
        g_w2t[j] = f2bs(W2[k * HID + n]);
    } else if (i < 2048 + 8192) {                     // W2R[n][k]
        const int j = i - (2048 + 4096);
        g_w2r[j] = f2bs(W2[j]);
    } else if (i < 2048 + 8192 + 2048) {              // W1R[n][k]
        const int j = i - (2048 + 8192), n = j >> 6;
        g_w1r[j] = (n < ND) ? f2bs(W1[j]) : (unsigned short)0;
    }
}

// ---------------- Fused kernel: block = 1 atom, 3 waves (192 thr) ---------
// Wave w owns rows 16w..16w+15 through ph1->fwd->bwd->8b with NO barriers:
// row-regions are wave-private; within-wave LDS RAW ordered by lgkmcnt.
// Only 3 __syncthreads: after ph0 (geometry), before 8c, before 8d.
// desc & sgd share a region with IDENTICAL 80B row stride so row ownership
// makes cross-wave access disjoint at any wave skew.
#define H1_OFF   0        // 6912: h1 then gz1 (ph4-7), wave-private rows
#define GZ2_OFF  6912     // 6912: gz2 (ph5-6) | sgf4/sgu4 overlay post-B2
#define SGF_OFF  6912     //   576: [3*48] f32
#define SGU_OFF  7488     //  1728: [(3*48)*3] f32
#define DESC_OFF 13824    // 3840: desc s16[48][40] | sgd f32[48][20]
#define SGD_OFF  13824
#define SS_OFF   17664    // 4704: S bf16 [48][49]
#define ST_OFF   22368    // 4704: T bf16 [48][49]
#define SU_OFF   27072    //  768: [4k+{x,y,z,d}]
#define SFC_OFF  27840    //  192
#define SFK_OFF  28032    //  192
#define SM_BYTES 28224

__global__ __launch_bounds__(192, 4) void k_fused(const float* __restrict__ rij,
                                                  const float* __restrict__ b1,
                                                  const float* __restrict__ b2,
                                                  const float* __restrict__ W3,
                                                  const float* __restrict__ b3,
                                                  float* __restrict__ out) {
    __shared__ __align__(16) char smem[SM_BYTES];
    short*          h1S   = (short*)(smem + H1_OFF);           // [row*72+n]
    short*          gz2S  = (short*)(smem + GZ2_OFF);          // [row*72+n]
    float*          sgf4  = (float*)(smem + SGF_OFF);
    float*          sgu4  = (float*)(smem + SGU_OFF);
    short*          descS = (short*)(smem + DESC_OFF);         // [row*40+j]
    float*          sgd   = (float*)(smem + SGD_OFF);          // [row*20+{0..16,17:eij}]
    unsigned short* sS    = (unsigned short*)(smem + SS_OFF);  // [k*49+l] bf16
    unsigned short* sT    = (unsigned short*)(smem + ST_OFF);  // [k*49+l] bf16
    float*          su    = (float*)(smem + SU_OFF);
    float*          sfc   = (float*)(smem + SFC_OFF);
    float*          sfk   = (float*)(smem + SFK_OFF);

    const int t = threadIdx.x;
    const int base3 = blockIdx.x * (K * 3);
    const int w0 = t >> 6, lane = t & 63, quad = lane >> 4, lm = lane & 15;
    const int row0 = 16 * w0;   // wave-owned row base

    // per-column scalars for all 4 N-tiles (prefetched, L2-broadcast)
    float b1v[4], b2v[4], w3v[4];
#pragma unroll
    for (int nt = 0; nt < 4; nt++) {
        b1v[nt] = b1[nt * 16 + lm];
        b2v[nt] = b2[nt * 16 + lm];
        w3v[nt] = W3[nt * 16 + lm];
    }
    const float b3v = b3[0];

    // ---- phase 0: per-pair geometry + rbf (sin recurrence) + K-pad ----
    if (t < K) {
        const float x = rij[base3 + 3 * t];
        const float y = rij[base3 + 3 * t + 1];
        const float z = rij[base3 + 3 * t + 2];
        float s2 = fmaxf(x * x + y * y + z * z, 1e-24f);
        const float inv = __builtin_amdgcn_rsqf(s2);
        const float d = s2 * inv;
        *(f4*)&su[4 * t] = (f4){x * inv, y * inv, z * inv, d};
        sfk[t] = 0.5f + 0.5f * __cosf(POC * d);
        const float fc = (d > RMIN_F) ? (0.5f + 0.5f * __cosf(AFC * (d - RMIN_F))) : 1.0f;
        sfc[t] = fc;
        // rbf: sin(n*POC*d), n=1..5 via recurrence s_{n+1} = 2cos*s_n - s_{n-1}
        float sn_, cn_;
        __sincosf(POC * d, &sn_, &cn_);
        const float sc = SQ * fc * inv;
        const float c2 = 2.0f * cn_;
        float sp = 0.0f, scur = sn_;
#pragma unroll
        for (int n = 0; n < NR; n++) {
            descS[t * 40 + n] = (short)f2bs(sc * scur);
            const float snx = c2 * scur - sp;
            sp = scur; scur = snx;
        }
#pragma unroll
        for (int c = ND; c < 32; c++) descS[t * 40 + c] = 0;  // K-pad
    }
    __syncthreads();   // B1: su/sfk/sfc/desc(rbf+pad) ready for all waves

    // ---- phase 1: 3-body descriptors (t = 4k+ch; wave w covers own rows) ----
    {
        const int k = t >> 2, ch = t & 3;
        const f4 uk = *(const f4*)&su[4 * k];
        const float* sul = &su[4 * (ch * 12)];
        f4 fkq[3];
        fkq[0] = *(const f4*)&sfk[ch * 12];
        fkq[1] = *(const f4*)&sfk[ch * 12 + 4];
        fkq[2] = *(const f4*)&sfk[ch * 12 + 8];
        f2 partv[6];
#pragma unroll
        for (int i = 0; i < 6; i++) partv[i] = (f2){0.0f, 0.0f};
#pragma unroll
        for (int li = 0; li < 12; li++) {
            const int l = ch * 12 + li;
            const f4 ul = *(const f4*)&sul[4 * li];
            float c = uk.x * ul.x + uk.y * ul.y + uk.z * ul.z;
            if (k == l) c = 0.0f;
            const float cp1 = c + 1.0f;
            const float e0 = __builtin_amdgcn_exp2f(N4L * cp1 * cp1) * fkq[li >> 2][li & 3];
            const float e1 = __builtin_amdgcn_exp2f(E1L * cp1);
            const float e2s = e1 * e1;
            const f2 e2v = {e2s, e2s};
            f2 tm = {e0, e0 * e1};
            partv[0] += tm;
#pragma unroll
            for (int i = 1; i < 6; i++) { tm *= e2v; partv[i] += tm; }
        }
#pragma unroll
        for (int i = 0; i < 6; i++) {
            partv[i].x = dpp_add<0x4E>(dpp_add<0xB1>(partv[i].x));
            partv[i].y = dpp_add<0x4E>(dpp_add<0xB1>(partv[i].y));
        }
        if (ch == 0) {
#pragma unroll
            for (int i = 0; i < 6; i++) {
                const int m0 = 2 * i, m1 = 2 * i + 1;
                descS[k * 40 + NR + m0] =
                    (short)f2bs(partv[i].x * __expf(CMC * (float)(m0 * m0)));
                descS[k * 40 + NR + m1] =
                    (short)f2bs(partv[i].y * __expf(CMC * (float)(m1 * m1)));
            }
        }
    }
    // NO barrier: wave w wrote desc rows 16w.., and reads only those below.

    float t1v[4][4];   // tanh(h1) for own rows, all 4 N-tiles
    float eijr[4];     // per-row energy (valid at lm==15)

    // ---- fwd1: h1 = tanh(desc @ W1 + b1), own 16 rows x all 64 cols ----
    {
        const frag_ab a = *(const frag_ab*)&descS[(row0 + lm) * 40 + quad * 8];
#pragma unroll
        for (int nt = 0; nt < 4; nt++) {
            const frag_ab bfr = *(const frag_ab*)&g_w1t[(nt * 16 + lm) * 32 + quad * 8];
            frag_cd acc = {b1v[nt], b1v[nt], b1v[nt], b1v[nt]};
            acc = __builtin_amdgcn_mfma_f32_16x16x32_bf16(a, bfr, acc, 0, 0, 0);
#pragma unroll
            for (int r = 0; r < 4; r++) {
                const float tv = fast_tanh(acc[r]);
                t1v[nt][r] = tv;
                h1S[(row0 + quad * 4 + r) * 72 + nt * 16 + lm] = (short)f2bs(tv);
            }
        }
    }

    // ---- fwd2: t2 = tanh(h1@W2+b2); row-sums -> eij; gz2 ----
    {
        const frag_ab a0 = *(const frag_ab*)&h1S[(row0 + lm) * 72 + quad * 8];
        const frag_ab a1 = *(const frag_ab*)&h1S[(row0 + lm) * 72 + 32 + quad * 8];
        const f4 fcv = *(const f4*)&sfc[row0 + quad * 4];
        float ep[4] = {0.0f, 0.0f, 0.0f, 0.0f};
#pragma unroll
        for (int nt = 0; nt < 4; nt++) {
            const frag_ab b0 = *(const frag_ab*)&g_w2t[(nt * 16 + lm) * 64 + quad * 8];
            const frag_ab b1f = *(const frag_ab*)&g_w2t[(nt * 16 + lm) * 64 + 32 + quad * 8];
            frag_cd acc = {b2v[nt], b2v[nt], b2v[nt], b2v[nt]};
            acc = __builtin_amdgcn_mfma_f32_16x16x32_bf16(a0, b0, acc, 0, 0, 0);
            acc = __builtin_amdgcn_mfma_f32_16x16x32_bf16(a1, b1f, acc, 0, 0, 0);
#pragma unroll
            for (int r = 0; r < 4; r++) {
                const float tv = fast_tanh(acc[r]);
                ep[r] = fmaf(tv, w3v[nt], ep[r]);
                gz2S[(row0 + quad * 4 + r) * 72 + nt * 16 + lm] =
                    (short)f2bs(fcv[r] * w3v[nt] * (1.0f - tv * tv));
            }
        }
        // 16-lane row sum (sum lands at lm==15)
#pragma unroll
        for (int r = 0; r < 4; r++)
            eijr[r] = dpp_add<0x118>(dpp_add<0x114>(dpp_add<0x112>(dpp_add<0x111>(ep[r]))));
    }

    // ---- bwd1: gz1 = (gz2 @ W2^T)*(1-t1^2) -> overwrite h1S (own rows) ----
    {
        const frag_ab a0 = *(const frag_ab*)&gz2S[(row0 + lm) * 72 + quad * 8];
        const frag_ab a1 = *(const frag_ab*)&gz2S[(row0 + lm) * 72 + 32 + quad * 8];
#pragma unroll
        for (int nt = 0; nt < 4; nt++) {
            const frag_ab b0 = *(const frag_ab*)&g_w2r[(nt * 16 + lm) * 64 + quad * 8];
            const frag_ab b1f = *(const frag_ab*)&g_w2r[(nt * 16 + lm) * 64 + 32 + quad * 8];
            frag_cd acc = {0.0f, 0.0f, 0.0f, 0.0f};
            acc = __builtin_amdgcn_mfma_f32_16x16x32_bf16(a0, b0, acc, 0, 0, 0);
            acc = __builtin_amdgcn_mfma_f32_16x16x32_bf16(a1, b1f, acc, 0, 0, 0);
#pragma unroll
            for (int r = 0; r < 4; r++) {
                const float g = acc[r] * (1.0f - t1v[nt][r] * t1v[nt][r]);
                h1S[(row0 + quad * 4 + r) * 72 + nt * 16 + lm] = (short)f2bs(g);
            }
        }
    }

    // ---- bwd2: gdesc = gz1 @ W1^T -> sgd (C_m pre-scaled); eij -> sgd ----
    {
        const frag_ab a0 = *(const frag_ab*)&h1S[(row0 + lm) * 72 + quad * 8];
        const frag_ab a1 = *(const frag_ab*)&h1S[(row0 + lm) * 72 + 32 + quad * 8];
#pragma unroll
        for (int nt = 0; nt < 2; nt++) {
            const frag_ab b0 = *(const frag_ab*)&g_w1r[(nt * 16 + lm) * 64 + quad * 8];
            const frag_ab b1f = *(const frag_ab*)&g_w1r[(nt * 16 + lm) * 64 + 32 + quad * 8];
            frag_cd acc = {0.0f, 0.0f, 0.0f, 0.0f};
            acc = __builtin_amdgcn_mfma_f32_16x16x32_bf16(a0, b0, acc, 0, 0, 0);
            acc = __builtin_amdgcn_mfma_f32_16x16x32_bf16(a1, b1f, acc, 0, 0, 0);
            const int n = nt * 16 + lm;
            if (n < ND) {
                const int mm = n - NR;
                const float cmul = (n >= NR) ? __expf(CMC * (float)(mm * mm)) : 1.0f;
#pragma unroll
                for (int r = 0; r < 4; r++)
                    sgd[(row0 + quad * 4 + r) * 20 + n] = acc[r] * cmul;
            }
        }
        if (lm == 15) {
#pragma unroll
            for (int r = 0; r < 4; r++)
                sgd[(row0 + quad * 4 + r) * 20 + 17] = eijr[r] + b3v;
        }
    }

    // ---- 8b: recompute cos; dual Horner; S,T -> LDS (bf16, own rows) ----
    {
        const int k = t >> 2, ch = t & 3;
        f2 gm[NM];
#pragma unroll
        for (int m = 0; m < NM; m++) {
            const float g = sgd[k * 20 + NR + m];
            gm[m] = (f2){g, (float)m * g};
        }
        const f4 uk = *(const f4*)&su[4 * k];
        const float* sul = &su[4 * (ch * 12)];
#pragma unroll
        for (int li = 0; li < 12; li++) {
            const int l = ch * 12 + li;
            const f4 ul = *(const f4*)&sul[4 * li];
            float c = uk.x * ul.x + uk.y * ul.y + uk.z * ul.z;
            if (k == l) c = 0.0f;
            const float cp1 = c + 1.0f;
            const float e0 = __builtin_amdgcn_exp2f(N4L * cp1 * cp1);
            const float x = __builtin_amdgcn_exp2f(E1L * cp1);
            const f2 xx = {x, x};
            f2 pd = gm[11];
#pragma unroll
            for (int m = 10; m >= 1; m--) pd = __builtin_elementwise_fma(pd, xx, gm[m]);
            const float Pv = fmaf(pd.x, x, gm[0].x);
            const float T = e0 * Pv;
            const float U = e0 * x * pd.y;
            const float Sp = fmaf(cp1, T, -(2.0f / 11.0f) * U);
            const float Sv = (k == l) ? 0.0f : (-8.0f) * Sp;
            sT[k * 49 + l] = f2bs(T);
            sS[k * 49 + l] = f2bs(Sv);
        }
    }
    __syncthreads();   // B2: full S/T matrices; gz2 dead -> overlay ok

    // ---- 8c: column reductions (3 waves x 16 rows each) ----
    if (lane < K) {
        float s = 0.0f;
#pragma unroll
        for (int kk = 16 * w0; kk < 16 * w0 + 16; kk++) s += bs2f(sT[kk * 49 + lane]);
        sgf4[w0 * 48 + lane] = s;

        const int k = lane;
        const float fk = sfk[k];
        float gx = 0.0f, gy = 0.0f, gz = 0.0f;
#pragma unroll
        for (int l = 16 * w0; l < 16 * w0 + 16; l++) {
            const float wgt = fmaf(bs2f(sS[k * 49 + l]), sfk[l],
                                   bs2f(sS[l * 49 + k]) * fk);
            const f4 ul = *(const f4*)&su[4 * l];
            gx = fmaf(wgt, ul.x, gx);
            gy = fmaf(wgt, ul.y, gy);
            gz = fmaf(wgt, ul.z, gz);
        }
        sgu4[(w0 * 48 + k) * 3 + 0] = gx;
        sgu4[(w0 * 48 + k) * 3 + 1] = gy;
        sgu4[(w0 * 48 + k) * 3 + 2] = gz;
    }
    __syncthreads();   // B3

    // ---- 8d: combine partials, assemble gradient, write out ----
    if (t < K) {
        const float sgf_t = sgf4[t] + sgf4[48 + t] + sgf4[96 + t];
        float gux = 0.0f, guy = 0.0f, guz = 0.0f;
#pragma unroll
        for (int ww = 0; ww < 3; ww++) {
            gux += sgu4[(ww * 48 + t) * 3 + 0];
            guy += sgu4[(ww * 48 + t) * 3 + 1];
            guz += sgu4[(ww * 48 + t) * 3 + 2];
        }
        const f4 uv = *(const f4*)&su[4 * t];
        const float d = uv.w;
        const float ux = uv.x, uy = uv.y, uz = uv.z;
        const float invd = __builtin_amdgcn_rcpf(d);
        float gfc = sgd[t * 20 + 17];
        float gdR = 0.0f;
#pragma unroll
        for (int n = 0; n < NR; n++) {
            const float bn = (float)(n + 1) * POC;
            float sn, cn;
            __sincosf(bn * d, &sn, &cn);
            const float g = sgd[t * 20 + n];
            gfc = fmaf(g, SQ * sn * invd, gfc);
            gdR = fmaf(g, SQ * (bn * cn - sn * invd) * invd, gdR);
        }
        const float fc = sfc[t];
        float dfc = 0.0f;
        if (d > RMIN_F) dfc = -0.5f * AFC * __sinf(AFC * (d - RMIN_F));
        const float dfcrik = -0.5f * POC * __sinf(POC * d);

        const float gd = fc * gdR + gfc * dfc + sgf_t * dfcrik;
        const float dot = gux * ux + guy * uy + guz * uz;

        out[base3 + 3 * t + 0] = fmaf(gd, ux, (gux - dot * ux) * invd);
        out[base3 + 3 * t + 1] = fmaf(gd, uy, (guy - dot * uy) * invd);
        out[base3 + 3 * t + 2] = fmaf(gd, uz, (guz - dot * uz) * invd);
    }
}

extern "C" void kernel_launch(void* const* d_in, const int* in_sizes, int n_in,
                              void* d_out, int out_size, void* d_ws, size_t ws_size,
                              hipStream_t stream) {
    (void)in_sizes; (void)n_in; (void)out_size; (void)d_ws; (void)ws_size;
    const float* rij = (const float*)d_in[0];
    // d_in[1] = unique_i (unused: dense K neighbors per atom)
    const float* W1 = (const float*)d_in[2];
    const float* b1 = (const float*)d_in[3];
    const float* W2 = (const float*)d_in[4];
    const float* b2 = (const float*)d_in[5];
    const float* W3 = (const float*)d_in[6];
    const float* b3 = (const float*)d_in[7];
    float* out = (float*)d_out;

    k_prep<<<48, 256, 0, stream>>>(W1, W2);
    k_fused<<<NATOMS, 192, 0, stream>>>(rij, b1, b2, W3, b3, out);
}

// Round 7
// 92.621 us; speedup vs baseline: 1.0233x; 1.0233x over previous
//
#include <hip/hip_runtime.h>
#include <hip/hip_bf16.h>

#define NATOMS 2048
#define K 48
#define NR 5
#define NM 12
#define ND 17
#define HID 64

#define PI_F 3.14159265358979f
#define CUT 3.0f
#define RMIN_F 3.5f
#define AFC (-6.28318530717959f)   /* pi/(CUT-RMIN) = pi/(-0.5) */
#define POC (PI_F / CUT)           /* pi/3 */
#define SQ 0.816496580927726f      /* sqrt(2/3) */
#define CMC (-0.132231404958678f)  /* -16/121 */
/* exp2-folded constants (x * log2(e)) */
#define N4L (-5.77078016355585f)   /* -4 * log2e */
#define E1L (2.09846551402031f)    /* (16/11) * log2e */
#define TL2 (2.88539008177793f)    /* 2 * log2e */

// Packed bf16 weight layouts (built once per launch by k_prep).
__device__ unsigned short g_w1t[64 * 32];  // [n=h][k=j]  (k>=17 zero)
__device__ unsigned short g_w2t[64 * 64];  // [n=h2][k=h1]
__device__ unsigned short g_w2r[64 * 64];  // [n=h1][k=h2]
__device__ unsigned short g_w1r[32 * 64];  // [n=j][k=h]  (n>=17 zero)

using frag_ab = __attribute__((ext_vector_type(8))) short;
using frag_cd = __attribute__((ext_vector_type(4))) float;
using f2 = __attribute__((ext_vector_type(2))) float;
using f4 = __attribute__((ext_vector_type(4))) float;

__device__ __forceinline__ float fast_tanh(float x) {
    const float t = __builtin_amdgcn_exp2f(TL2 * x);
    return 1.0f - 2.0f * __builtin_amdgcn_rcpf(t + 1.0f);
}

__device__ __forceinline__ unsigned short f2bs(float x) {
    __hip_bfloat16 b = __float2bfloat16(x);
    return __builtin_bit_cast(unsigned short, b);
}

__device__ __forceinline__ float bs2f(unsigned short u) {
    return __builtin_bit_cast(float, ((unsigned)u) << 16);
}

// DPP cross-lane add. 0xB1/0x4E = quad_perm xor1/xor2 (butterfly).
// 0x110|s = row_shr s (16-lane sum lands in lane 15 of each DPP row).
template <int CTRL>
__device__ __forceinline__ float dpp_add(float x) {
    const int y = __builtin_amdgcn_update_dpp(
        0, __builtin_bit_cast(int, x), CTRL, 0xF, 0xF, true);
    return x + __builtin_bit_cast(float, y);
}

// ---------------- Kernel 0: pack weights into MFMA-ready bf16 layouts -----
__global__ __launch_bounds__(256) void k_prep(const float* __restrict__ W1,
                                              const float* __restrict__ W2) {
    const int i = blockIdx.x * 256 + threadIdx.x;  // grid covers 12288
    if (i < 2048) {                                   // W1T[n][k]
        const int n = i >> 5, k = i & 31;
        g_w1t[i] = (k < ND) ? f2bs(W1[k * HID + n]) : (unsigned short)0;
    } else if (i < 2048 + 4096) {                     // W2T[n][k]
        const int j = i - 2048, n = j >> 6, k = j & 63;
        g_w2t[j] = f2bs(W2[k * HID + n]);
    } else if (i < 2048 + 8192) {                     // W2R[n][k]
        const int j = i - (2048 + 4096);
        g_w2r[j] = f2bs(W2[j]);
    } else if (i < 2048 + 8192 + 2048) {              // W1R[n][k]
        const int j = i - (2048 + 8192), n = j >> 6;
        g_w1r[j] = (n < ND) ? f2bs(W1[j]) : (unsigned short)0;
    }
}

// ---------------- Fused kernel: block = 1 atom (48 pairs), 4 waves --------
// CODE-SIZE-REDUCED variant: all large loops rolled (#pragma unroll 1) to
// shrink the instruction footprint ~4x (I-fetch theory: every prior variant
// was ~40KB straight-line code streamed once per wave -> L1I thrash).
// No runtime-indexed register arrays inside rolled loops (scratch rule):
// t1 re-read from h1S (bf16), sfk read scalar, Horner/gm stay unrolled.
// LDS layout identical to R3 (20,448 B):
//  A @0     (6912): h1S [48][72]s16 (fwd/bwd) | sT bf16 [48][49] (8b-8c)
//  B @6912  (6912): descS [48][40]s16 | sgd [48][19]f32 + sgf4 + sgu4
//  C @13824 (4704): sS bf16 [48][49]
//  SE @18528 (768), SU @19296 (768), SFC @20064 (192), SFK @20256 (192)
#define H1_OFF   0
#define ST_OFF   0
#define DESC_OFF 6912
#define GZ2_OFF  6912
#define SGD_OFF  6912
#define SGF_OFF  10560
#define SGU_OFF  11328
#define SS_OFF   13824
#define SE_OFF   18528
#define SU_OFF   19296
#define SFC_OFF  20064
#define SFK_OFF  20256
#define SM_BYTES 20448

__global__ __launch_bounds__(256, 6) void k_fused(const float* __restrict__ rij,
                                                  const float* __restrict__ b1,
                                                  const float* __restrict__ b2,
                                                  const float* __restrict__ W3,
                                                  const float* __restrict__ b3,
                                                  float* __restrict__ out) {
    __shared__ __align__(16) char smem[SM_BYTES];
    short*          h1S   = (short*)(smem + H1_OFF);           // [row*72+n]
    unsigned short* sT    = (unsigned short*)(smem + ST_OFF);  // [k*49+l] bf16
    short*          descS = (short*)(smem + DESC_OFF);         // [row*40+j]
    short*          gz2S  = (short*)(smem + GZ2_OFF);          // [row*72+n]
    float*          sgd   = (float*)(smem + SGD_OFF);          // [k*19+{0..16,17:eij}]
    float*          sgf4  = (float*)(smem + SGF_OFF);          // [w*48+l]
    float*          sgu4  = (float*)(smem + SGU_OFF);          // [(w*48+k)*3+c]
    unsigned short* sS    = (unsigned short*)(smem + SS_OFF);  // [k*49+l] bf16
    float*          se    = (float*)(smem + SE_OFF);           // [w*48+row]
    float*          su    = (float*)(smem + SU_OFF);           // [4k+{x,y,z,d}]
    float*          sfc   = (float*)(smem + SFC_OFF);
    float*          sfk   = (float*)(smem + SFK_OFF);

    const int t = threadIdx.x;
    const int base3 = blockIdx.x * (K * 3);
    const int w = t >> 6, lane = t & 63, quad = lane >> 4, lm = lane & 15;
    const int n0 = w * 16 + lm;

    // per-wave fixed MFMA B-fragments (one N-tile per wave) + scalars
    const frag_ab wf1  = *(const frag_ab*)&g_w1t[n0 * 32 + quad * 8];
    const frag_ab wf2a = *(const frag_ab*)&g_w2t[n0 * 64 + quad * 8];
    const frag_ab wf2b = *(const frag_ab*)&g_w2t[n0 * 64 + 32 + quad * 8];
    const frag_ab wr2a = *(const frag_ab*)&g_w2r[n0 * 64 + quad * 8];
    const frag_ab wr2b = *(const frag_ab*)&g_w2r[n0 * 64 + 32 + quad * 8];
    const float bias1 = b1[n0];
    const float bias2 = b2[n0];
    const float w3n   = W3[n0];
    const float b3v   = b3[0];

    // ---- phase 0: geometry + rbf (sin/cos recurrence) + K-pad ----
    if (t < K) {
        const float x = rij[base3 + 3 * t];
        const float y = rij[base3 + 3 * t + 1];
        const float z = rij[base3 + 3 * t + 2];
        float s2 = fmaxf(x * x + y * y + z * z, 1e-24f);
        const float inv = __builtin_amdgcn_rsqf(s2);
        const float d = s2 * inv;
        *(f4*)&su[4 * t] = (f4){x * inv, y * inv, z * inv, d};
        sfk[t] = 0.5f + 0.5f * __cosf(POC * d);
        const float fc = (d > RMIN_F) ? (0.5f + 0.5f * __cosf(AFC * (d - RMIN_F))) : 1.0f;
        sfc[t] = fc;
        float s1, c1;
        __sincosf(POC * d, &s1, &c1);
        const float sc = SQ * fc * inv;
        float sn = s1, cn = c1;
#pragma unroll 1
        for (int n = 0; n < NR; n++) {
            descS[t * 40 + n] = (short)f2bs(sc * sn);
            const float snx = sn * c1 + cn * s1;
            cn = cn * c1 - sn * s1;
            sn = snx;
        }
#pragma unroll 1
        for (int c = ND; c < 32; c++) descS[t * 40 + c] = 0;  // K-pad
    }
    __syncthreads();   // B1

    // ---- phase 1: 3-body descriptors (t = 4k+ch, DPP quad-reduced) ----
    if (t < 192) {
        const int k = t >> 2, ch = t & 3;
        const f4 uk = *(const f4*)&su[4 * k];
        const float* sul = &su[4 * (ch * 12)];
        f2 partv[6];
#pragma unroll
        for (int i = 0; i < 6; i++) partv[i] = (f2){0.0f, 0.0f};
#pragma unroll 1
        for (int li = 0; li < 12; li++) {
            const int l = ch * 12 + li;
            const f4 ul = *(const f4*)&sul[4 * li];
            float c = uk.x * ul.x + uk.y * ul.y + uk.z * ul.z;
            if (k == l) c = 0.0f;
            const float cp1 = c + 1.0f;
            const float e0 = __builtin_amdgcn_exp2f(N4L * cp1 * cp1) * sfk[l];
            const float e1 = __builtin_amdgcn_exp2f(E1L * cp1);
            const float e2s = e1 * e1;
            const f2 e2v = {e2s, e2s};
            f2 tm = {e0, e0 * e1};
            partv[0] += tm;
#pragma unroll
            for (int i = 1; i < 6; i++) { tm *= e2v; partv[i] += tm; }
        }
#pragma unroll
        for (int i = 0; i < 6; i++) {
            partv[i].x = dpp_add<0x4E>(dpp_add<0xB1>(partv[i].x));
            partv[i].y = dpp_add<0x4E>(dpp_add<0xB1>(partv[i].y));
        }
        if (ch == 0) {
#pragma unroll
            for (int i = 0; i < 6; i++) {
                const int m0 = 2 * i, m1 = 2 * i + 1;
                descS[k * 40 + NR + m0] =
                    (short)f2bs(partv[i].x * __expf(CMC * (float)(m0 * m0)));
                descS[k * 40 + NR + m1] =
                    (short)f2bs(partv[i].y * __expf(CMC * (float)(m1 * m1)));
            }
        }
    }
    __syncthreads();   // B2

    // ---- fwd1: h1 = tanh(desc @ W1 + b1)  (N-split: wave w owns cols n0) ----
#pragma unroll 1
    for (int mt = 0; mt < 3; mt++) {
        const frag_ab a = *(const frag_ab*)&descS[(mt * 16 + lm) * 40 + quad * 8];
        frag_cd acc = {bias1, bias1, bias1, bias1};
        acc = __builtin_amdgcn_mfma_f32_16x16x32_bf16(a, wf1, acc, 0, 0, 0);
#pragma unroll
        for (int r = 0; r < 4; r++)
            h1S[(mt * 16 + quad * 4 + r) * 72 + n0] = (short)f2bs(fast_tanh(acc[r]));
    }
    __syncthreads();   // B3

    // ---- fwd2: t2 = tanh(h1@W2+b2); eij row-sums -> se; gz2 ----
#pragma unroll 1
    for (int mt = 0; mt < 3; mt++) {
        const frag_ab a0 = *(const frag_ab*)&h1S[(mt * 16 + lm) * 72 + quad * 8];
        const frag_ab a1 = *(const frag_ab*)&h1S[(mt * 16 + lm) * 72 + 32 + quad * 8];
        frag_cd acc = {bias2, bias2, bias2, bias2};
        acc = __builtin_amdgcn_mfma_f32_16x16x32_bf16(a0, wf2a, acc, 0, 0, 0);
        acc = __builtin_amdgcn_mfma_f32_16x16x32_bf16(a1, wf2b, acc, 0, 0, 0);
        float ep[4];
#pragma unroll
        for (int r = 0; r < 4; r++) {
            const int row = mt * 16 + quad * 4 + r;
            const float tv = fast_tanh(acc[r]);
            ep[r] = tv * w3n;
            gz2S[row * 72 + n0] = (short)f2bs(sfc[row] * w3n * (1.0f - tv * tv));
        }
#pragma unroll
        for (int r = 0; r < 4; r++)
            ep[r] = dpp_add<0x118>(dpp_add<0x114>(dpp_add<0x112>(dpp_add<0x111>(ep[r]))));
        if (lm == 15) {
#pragma unroll
            for (int r = 0; r < 4; r++) se[w * 48 + mt * 16 + quad * 4 + r] = ep[r];
        }
    }
    __syncthreads();   // B4

    // ---- bwd1: gz1 = (gz2 @ W2^T)*(1-t1^2); t1 re-read from h1S (bf16) ----
#pragma unroll 1
    for (int mt = 0; mt < 3; mt++) {
        const frag_ab a0 = *(const frag_ab*)&gz2S[(mt * 16 + lm) * 72 + quad * 8];
        const frag_ab a1 = *(const frag_ab*)&gz2S[(mt * 16 + lm) * 72 + 32 + quad * 8];
        frag_cd acc = {0.0f, 0.0f, 0.0f, 0.0f};
        acc = __builtin_amdgcn_mfma_f32_16x16x32_bf16(a0, wr2a, acc, 0, 0, 0);
        acc = __builtin_amdgcn_mfma_f32_16x16x32_bf16(a1, wr2b, acc, 0, 0, 0);
#pragma unroll
        for (int r = 0; r < 4; r++) {
            const int row = mt * 16 + quad * 4 + r;
            const float tv = bs2f((unsigned short)h1S[row * 72 + n0]);
            h1S[row * 72 + n0] = (short)f2bs(acc[r] * (1.0f - tv * tv));
        }
    }
    __syncthreads();   // B5

    // ---- bwd2: gdesc = gz1 @ W1^T -> sgd (C_m pre-scaled); eij -> sgd ----
#pragma unroll 1
    for (int tid = w; tid < 6; tid += 4) {
        const int mt = tid >> 1, nt = tid & 1, n = nt * 16 + lm;
        const frag_ab b0 = *(const frag_ab*)&g_w1r[n * 64 + quad * 8];
        const frag_ab b1f = *(const frag_ab*)&g_w1r[n * 64 + 32 + quad * 8];
        const frag_ab a0 = *(const frag_ab*)&h1S[(mt * 16 + lm) * 72 + quad * 8];
        const frag_ab a1 = *(const frag_ab*)&h1S[(mt * 16 + lm) * 72 + 32 + quad * 8];
        frag_cd acc = {0.0f, 0.0f, 0.0f, 0.0f};
        acc = __builtin_amdgcn_mfma_f32_16x16x32_bf16(a0, b0, acc, 0, 0, 0);
        acc = __builtin_amdgcn_mfma_f32_16x16x32_bf16(a1, b1f, acc, 0, 0, 0);
        if (n < ND) {
            const int mm = n - NR;
            const float cmul = (n >= NR) ? __expf(CMC * (float)(mm * mm)) : 1.0f;
#pragma unroll
            for (int r = 0; r < 4; r++)
                sgd[(mt * 16 + quad * 4 + r) * 19 + n] = acc[r] * cmul;
        }
    }
    if (t < K)
        sgd[t * 19 + 17] = se[t] + se[48 + t] + se[96 + t] + se[144 + t] + b3v;
    __syncthreads();   // B6

    // ---- 8b: recompute cos; dual Horner; S,T -> LDS (bf16) ----
    if (t < 192) {
        const int k = t >> 2, ch = t & 3;
        f2 gm[NM];
#pragma unroll
        for (int m = 0; m < NM; m++) {
            const float g = sgd[k * 19 + NR + m];
            gm[m] = (f2){g, (float)m * g};
        }
        const f4 uk = *(const f4*)&su[4 * k];
        const float* sul = &su[4 * (ch * 12)];
#pragma unroll 1
        for (int li = 0; li < 12; li++) {
            const int l = ch * 12 + li;
            const f4 ul = *(const f4*)&sul[4 * li];
            float c = uk.x * ul.x + uk.y * ul.y + uk.z * ul.z;
            if (k == l) c = 0.0f;
            const float cp1 = c + 1.0f;
            const float e0 = __builtin_amdgcn_exp2f(N4L * cp1 * cp1);
            const float x = __builtin_amdgcn_exp2f(E1L * cp1);
            const f2 xx = {x, x};
            f2 pd = gm[11];
#pragma unroll
            for (int m = 10; m >= 1; m--) pd = __builtin_elementwise_fma(pd, xx, gm[m]);
            const float Pv = fmaf(pd.x, x, gm[0].x);
            const float T = e0 * Pv;
            const float U = e0 * x * pd.y;
            const float Sp = fmaf(cp1, T, -(2.0f / 11.0f) * U);
            const float Sv = (k == l) ? 0.0f : (-8.0f) * Sp;
            sT[k * 49 + l] = f2bs(T);
            sS[k * 49 + l] = f2bs(Sv);
        }
    }
    __syncthreads();   // B7

    // ---- 8c: partial column reductions, all 4 waves ----
    if (lane < K) {
        float s = 0.0f;
#pragma unroll 1
        for (int kk = 12 * w; kk < 12 * w + 12; kk++) s += bs2f(sT[kk * 49 + lane]);
        sgf4[w * 48 + lane] = s;

        const int k = lane;
        const float fk = sfk[k];
        float gx = 0.0f, gy = 0.0f, gz = 0.0f;
#pragma unroll 1
        for (int l = 12 * w; l < 12 * w + 12; l++) {
            const float wgt = fmaf(bs2f(sS[k * 49 + l]), sfk[l],
                                   bs2f(sS[l * 49 + k]) * fk);
            const f4 ul = *(const f4*)&su[4 * l];
            gx = fmaf(wgt, ul.x, gx);
            gy = fmaf(wgt, ul.y, gy);
            gz = fmaf(wgt, ul.z, gz);
        }
        sgu4[(w * 48 + k) * 3 + 0] = gx;
        sgu4[(w * 48 + k) * 3 + 1] = gy;
        sgu4[(w * 48 + k) * 3 + 2] = gz;
    }
    __syncthreads();   // B8

    // ---- 8d: combine partials, assemble gradient, write out ----
    if (t < K) {
        const float sgf_t = sgf4[t] + sgf4[48 + t] + sgf4[96 + t] + sgf4[144 + t];
        float gux = 0.0f, guy = 0.0f, guz = 0.0f;
#pragma unroll
        for (int ww = 0; ww < 4; ww++) {
            gux += sgu4[(ww * 48 + t) * 3 + 0];
            guy += sgu4[(ww * 48 + t) * 3 + 1];
            guz += sgu4[(ww * 48 + t) * 3 + 2];
        }
        const f4 uv = *(const f4*)&su[4 * t];
        const float d = uv.w;
        const float ux = uv.x, uy = uv.y, uz = uv.z;
        const float invd = __builtin_amdgcn_rcpf(d);
        float gfc = sgd[t * 19 + 17];
        float gdR = 0.0f;
        float s1, c1;
        __sincosf(POC * d, &s1, &c1);
        float sn = s1, cn = c1, bn = POC;
#pragma unroll 1
        for (int n = 0; n < NR; n++) {
            const float g = sgd[t * 19 + n];
            gfc = fmaf(g, SQ * sn * invd, gfc);
            gdR = fmaf(g, SQ * (bn * cn - sn * invd) * invd, gdR);
            const float snx = sn * c1 + cn * s1;
            cn = cn * c1 - sn * s1;
            sn = snx;
            bn += POC;
        }
        const float fc = sfc[t];
        float dfc = 0.0f;
        if (d > RMIN_F) dfc = -0.5f * AFC * __sinf(AFC * (d - RMIN_F));
        const float dfcrik = -0.5f * POC * __sinf(POC * d);

        const float gd = fc * gdR + gfc * dfc + sgf_t * dfcrik;
        const float dot = gux * ux + guy * uy + guz * uz;

        out[base3 + 3 * t + 0] = fmaf(gd, ux, (gux - dot * ux) * invd);
        out[base3 + 3 * t + 1] = fmaf(gd, uy, (guy - dot * uy) * invd);
        out[base3 + 3 * t + 2] = fmaf(gd, uz, (guz - dot * uz) * invd);
    }
}

extern "C" void kernel_launch(void* const* d_in, const int* in_sizes, int n_in,
                              void* d_out, int out_size, void* d_ws, size_t ws_size,
                              hipStream_t stream) {
    (void)in_sizes; (void)n_in; (void)out_size; (void)d_ws; (void)ws_size;
    const float* rij = (const float*)d_in[0];
    // d_in[1] = unique_i (unused: dense K neighbors per atom)
    const float* W1 = (const float*)d_in[2];
    const float* b1 = (const float*)d_in[3];
    const float* W2 = (const float*)d_in[4];
    const float* b2 = (const float*)d_in[5];
    const float* W3 = (const float*)d_in[6];
    const float* b3 = (const float*)d_in[7];
    float* out = (float*)d_out;

    k_prep<<<48, 256, 0, stream>>>(W1, W2);
    k_fused<<<NATOMS, 256, 0, stream>>>(rij, b1, b2, W3, b3, out);
}